// Round 1
// baseline (116.963 us; speedup 1.0000x reference)
//
#include <hip/hip_runtime.h>
#include <math.h>

#define N_SAMPLES 131072
#define HIDDEN 1024

__device__ __forceinline__ float softplusf(float v) {
    return fmaxf(v, 0.0f) + log1pf(expf(-fabsf(v)));
}
__device__ __forceinline__ double softplusd(double v) {
    return fmax(v, 0.0) + log1p(exp(-fabs(v)));
}
__device__ __forceinline__ double kl_term(double mu, double sigma, double prior) {
    double r = sigma / prior;
    double m = mu / prior;
    return 0.5 * (-2.0 * log(r) - 1.0 + r * r + m * m);
}

// ---------------------------------------------------------------------------
// Kernel 1: sample weights, KL, breakpoints, bitonic sort, prefix-scan LUT.
// Single block of 1024 threads (one thread per hidden unit).
// ---------------------------------------------------------------------------
__global__ __launch_bounds__(1024) void bbb_prep_kernel(
    const float* __restrict__ W1_mu, const float* __restrict__ W1_rho,
    const float* __restrict__ b1_mu, const float* __restrict__ b1_rho,
    const float* __restrict__ W2_mu, const float* __restrict__ W2_rho,
    const float* __restrict__ b2_mu, const float* __restrict__ b2_rho,
    const float* __restrict__ eps_W1, const float* __restrict__ eps_b1,
    const float* __restrict__ eps_W2, const float* __restrict__ eps_b2,
    float* __restrict__ t_out,    // [2*HIDDEN] sorted breakpoints, +inf padded
    float4* __restrict__ lut_out, // [HIDDEN+1] {slopeA, interA, slopeB, interB}
    float* __restrict__ kl_out)   // scalar
{
    __shared__ float   s_key[HIDDEN];
    __shared__ int     s_perm[HIDDEN];
    __shared__ double  s_red[HIDDEN];
    __shared__ double4 s_d4[HIDDEN];
    __shared__ double4 s_base;

    const int tid = threadIdx.x;
    const double p1 = 4.0;
    const double p2 = 2.25 / 32.0;   // 2.25/sqrt(1024)

    // ---- sampled parameters for unit tid ----
    double w1  = (double)W1_mu[tid] + softplusd((double)W1_rho[tid]) * (double)eps_W1[tid];
    double bb1 = (double)b1_mu[tid] + softplusd((double)b1_rho[tid]) * (double)eps_b1[tid];
    double w2a = (double)W2_mu[tid]          + softplusd((double)W2_rho[tid])          * (double)eps_W2[tid];
    double w2b = (double)W2_mu[HIDDEN + tid] + softplusd((double)W2_rho[HIDDEN + tid]) * (double)eps_W2[HIDDEN + tid];

    // ---- KL reduction (double) ----
    double kl = 0.0;
    kl += kl_term((double)W1_mu[tid], softplusd((double)W1_rho[tid]), p1);
    kl += kl_term((double)b1_mu[tid], softplusd((double)b1_rho[tid]), p1);
    kl += kl_term((double)W2_mu[tid],          softplusd((double)W2_rho[tid]),          p2);
    kl += kl_term((double)W2_mu[HIDDEN + tid], softplusd((double)W2_rho[HIDDEN + tid]), p2);
    if (tid < 2) {
        kl += kl_term((double)b2_mu[tid], softplusd((double)b2_rho[tid]), p2);
    }
    s_red[tid] = kl;
    __syncthreads();
    for (int off = 512; off > 0; off >>= 1) {
        if (tid < off) s_red[tid] += s_red[tid + off];
        __syncthreads();
    }
    if (tid == 0) *kl_out = (float)s_red[0];

    // ---- base (x -> -inf) contributions ----
    // At x = -inf: units with w1 < 0 are active; w1 == 0 units active iff bb1 > 0.
    double4 b4 = {0.0, 0.0, 0.0, 0.0};
    if (w1 < 0.0) {
        b4.x = w1 * w2a;  b4.y = bb1 * w2a;
        b4.z = w1 * w2b;  b4.w = bb1 * w2b;
    } else if (w1 == 0.0 && bb1 > 0.0) {
        b4.y = bb1 * w2a; b4.w = bb1 * w2b;
    }
    s_d4[tid] = b4;
    __syncthreads();
    for (int off = 512; off > 0; off >>= 1) {
        if (tid < off) {
            s_d4[tid].x += s_d4[tid + off].x;
            s_d4[tid].y += s_d4[tid + off].y;
            s_d4[tid].z += s_d4[tid + off].z;
            s_d4[tid].w += s_d4[tid + off].w;
        }
        __syncthreads();
    }
    if (tid == 0) {
        double bb2a = (double)b2_mu[0] + softplusd((double)b2_rho[0]) * (double)eps_b2[0];
        double bb2b = (double)b2_mu[1] + softplusd((double)b2_rho[1]) * (double)eps_b2[1];
        double4 sb;
        sb.x = s_d4[0].x;  sb.y = s_d4[0].y + bb2a;
        sb.z = s_d4[0].z;  sb.w = s_d4[0].w + bb2b;
        s_base = sb;
    }

    // ---- breakpoint keys ----
    float key;
    if (w1 != 0.0) key = (float)(-bb1 / w1);
    else           key = __builtin_huge_valf();
    __syncthreads();   // also guards s_base write above
    s_key[tid]  = key;
    s_perm[tid] = tid;
    __syncthreads();

    // ---- bitonic sort (key, perm) ascending ----
    for (int k = 2; k <= HIDDEN; k <<= 1) {
        for (int j = k >> 1; j > 0; j >>= 1) {
            int ixj = tid ^ j;
            if (ixj > tid) {
                bool up = ((tid & k) == 0);
                float a = s_key[tid], b = s_key[ixj];
                if ((a > b) == up) {
                    s_key[tid] = b; s_key[ixj] = a;
                    int pa = s_perm[tid];
                    s_perm[tid] = s_perm[ixj];
                    s_perm[ixj] = pa;
                }
            }
            __syncthreads();
        }
    }

    // ---- deltas in sorted order (recompute from globals, L1-resident) ----
    int jj = s_perm[tid];
    double w1s  = (double)W1_mu[jj] + softplusd((double)W1_rho[jj]) * (double)eps_W1[jj];
    double bb1s = (double)b1_mu[jj] + softplusd((double)b1_rho[jj]) * (double)eps_b1[jj];
    double w2as = (double)W2_mu[jj]          + softplusd((double)W2_rho[jj])          * (double)eps_W2[jj];
    double w2bs = (double)W2_mu[HIDDEN + jj] + softplusd((double)W2_rho[HIDDEN + jj]) * (double)eps_W2[HIDDEN + jj];

    double4 d4 = {0.0, 0.0, 0.0, 0.0};
    if (w1s > 0.0) {          // crossing t upward: unit activates
        d4.x =  w1s * w2as;  d4.y =  bb1s * w2as;
        d4.z =  w1s * w2bs;  d4.w =  bb1s * w2bs;
    } else if (w1s < 0.0) {   // crossing t upward: unit deactivates
        d4.x = -w1s * w2as;  d4.y = -bb1s * w2as;
        d4.z = -w1s * w2bs;  d4.w = -bb1s * w2bs;
    }
    __syncthreads();  // s_d4 reuse
    s_d4[tid] = d4;
    __syncthreads();

    // ---- Hillis-Steele inclusive scan over double4 ----
    for (int off = 1; off < HIDDEN; off <<= 1) {
        double4 v = s_d4[tid];
        if (tid >= off) {
            double4 u = s_d4[tid - off];
            v.x += u.x; v.y += u.y; v.z += u.z; v.w += u.w;
        }
        __syncthreads();
        s_d4[tid] = v;
        __syncthreads();
    }

    // ---- write LUT + sorted breakpoints ----
    t_out[tid]          = s_key[tid];
    t_out[HIDDEN + tid] = __builtin_huge_valf();  // padding for branchless search
    double4 pre = s_d4[tid];
    lut_out[tid + 1] = make_float4((float)(s_base.x + pre.x),
                                   (float)(s_base.y + pre.y),
                                   (float)(s_base.z + pre.z),
                                   (float)(s_base.w + pre.w));
    if (tid == 0) {
        lut_out[0] = make_float4((float)s_base.x, (float)s_base.y,
                                 (float)s_base.z, (float)s_base.w);
    }
}

// ---------------------------------------------------------------------------
// Kernel 2: per-sample piecewise-linear evaluation.
// ---------------------------------------------------------------------------
__global__ __launch_bounds__(256) void bbb_eval_kernel(
    const float* __restrict__ x,
    const float* __restrict__ t_sorted,  // [2*HIDDEN]
    const float4* __restrict__ lut,      // [HIDDEN+1]
    float* __restrict__ means,
    float* __restrict__ stds)
{
    __shared__ float  s_t[2 * HIDDEN];
    __shared__ float4 s_lut[HIDDEN + 1];

    for (int i = threadIdx.x; i < 2 * HIDDEN; i += blockDim.x) s_t[i] = t_sorted[i];
    for (int i = threadIdx.x; i < HIDDEN + 1; i += blockDim.x) s_lut[i] = lut[i];
    __syncthreads();

    int gid = blockIdx.x * blockDim.x + threadIdx.x;
    float xv = x[gid];

    // branchless count of breakpoints <= xv (array padded with +inf)
    int idx = 0;
    #pragma unroll
    for (int s = HIDDEN; s > 0; s >>= 1) {
        idx += (s_t[idx + s - 1] <= xv) ? s : 0;
    }

    float4 c = s_lut[idx];
    float m = fmaf(xv, c.x, c.y);
    float u = fmaf(xv, c.z, c.w);
    means[gid] = m;
    stds[gid]  = 1e-5f + softplusf(u);
}

extern "C" void kernel_launch(void* const* d_in, const int* in_sizes, int n_in,
                              void* d_out, int out_size, void* d_ws, size_t ws_size,
                              hipStream_t stream) {
    const float* x      = (const float*)d_in[0];
    const float* W1_mu  = (const float*)d_in[1];
    const float* W1_rho = (const float*)d_in[2];
    const float* b1_mu  = (const float*)d_in[3];
    const float* b1_rho = (const float*)d_in[4];
    const float* W2_mu  = (const float*)d_in[5];
    const float* W2_rho = (const float*)d_in[6];
    const float* b2_mu  = (const float*)d_in[7];
    const float* b2_rho = (const float*)d_in[8];
    const float* eps_W1 = (const float*)d_in[9];
    const float* eps_b1 = (const float*)d_in[10];
    const float* eps_W2 = (const float*)d_in[11];
    const float* eps_b2 = (const float*)d_in[12];

    float* out = (float*)d_out;
    float*  t_ws   = (float*)d_ws;                                  // 2048 floats
    float4* lut_ws = (float4*)((char*)d_ws + 2 * HIDDEN * sizeof(float)); // 1025 float4

    bbb_prep_kernel<<<1, HIDDEN, 0, stream>>>(
        W1_mu, W1_rho, b1_mu, b1_rho, W2_mu, W2_rho, b2_mu, b2_rho,
        eps_W1, eps_b1, eps_W2, eps_b2,
        t_ws, lut_ws, out + 2 * N_SAMPLES);

    bbb_eval_kernel<<<N_SAMPLES / 256, 256, 0, stream>>>(
        x, t_ws, lut_ws, out, out + N_SAMPLES);
}